// Round 7
// baseline (2030.138 us; speedup 1.0000x reference)
//
#include <hip/hip_runtime.h>
#include <stdint.h>

#define HID 2048
#define ITR 5632
#define NE 8
#define TT 8192

typedef __attribute__((ext_vector_type(4))) float f4;
typedef __attribute__((ext_vector_type(8))) short s8v;      // 8 bf16 (MFMA frag)
typedef __attribute__((ext_vector_type(4))) float acc4;     // MFMA accum
typedef __attribute__((ext_vector_type(4))) unsigned short u4v;
typedef __attribute__((ext_vector_type(8))) unsigned short u8v;

__device__ __forceinline__ unsigned short f2bf(float f) {
    union { float f; uint32_t u; } v; v.f = f;
    uint32_t u = v.u;
    return (unsigned short)((u + 0x7FFFu + ((u >> 16) & 1u)) >> 16);
}

__device__ __forceinline__ void gload16(const unsigned short* g, unsigned short* l) {
    __builtin_amdgcn_global_load_lds(
        (const __attribute__((address_space(1))) unsigned int*)g,
        (__attribute__((address_space(3))) unsigned int*)l, 16, 0, 0);
}

#define MFMA16(a, b, c) __builtin_amdgcn_mfma_f32_16x16x32_bf16(a, b, c, 0, 0, 0)

// ---------- fp32 -> bf16 bulk convert ----------
__global__ __launch_bounds__(256) void k_cvt(const float* __restrict__ src,
                                             unsigned short* __restrict__ dst) {
    size_t i = ((size_t)blockIdx.x * 256 + threadIdx.x) * 8;
    f4 a = *(const f4*)(src + i);
    f4 b = *(const f4*)(src + i + 4);
    u8v o;
    o[0]=f2bf(a.x); o[1]=f2bf(a.y); o[2]=f2bf(a.z); o[3]=f2bf(a.w);
    o[4]=f2bf(b.x); o[5]=f2bf(b.y); o[6]=f2bf(b.z); o[7]=f2bf(b.w);
    *(u8v*)(dst + i) = o;
}

#define WBLK 45056
__global__ __launch_bounds__(256) void k_cvtW(const float* __restrict__ a,
                                              const float* __restrict__ b,
                                              const float* __restrict__ c,
                                              unsigned short* __restrict__ oa,
                                              unsigned short* __restrict__ ob,
                                              unsigned short* __restrict__ oc) {
    int bb = blockIdx.x;
    const float* s; unsigned short* d;
    if (bb < WBLK)            { s = a; d = oa; }
    else if (bb < 2 * WBLK)   { s = b; d = ob; bb -= WBLK; }
    else                      { s = c; d = oc; bb -= 2 * WBLK; }
    size_t i = ((size_t)bb * 256 + threadIdx.x) * 8;
    f4 va = *(const f4*)(s + i);
    f4 vb = *(const f4*)(s + i + 4);
    u8v o;
    o[0]=f2bf(va.x); o[1]=f2bf(va.y); o[2]=f2bf(va.z); o[3]=f2bf(va.w);
    o[4]=f2bf(vb.x); o[5]=f2bf(vb.y); o[6]=f2bf(vb.z); o[7]=f2bf(vb.w);
    *(u8v*)(d + i) = o;
}

// ---------- router ----------
__global__ __launch_bounds__(256) void k_router(const float* __restrict__ x,
                                                const float* __restrict__ rw,
                                                const float* __restrict__ rb,
                                                int* __restrict__ cnt,
                                                int* __restrict__ tokL,
                                                int* __restrict__ slotL,
                                                float* __restrict__ gateL) {
    int lane = threadIdx.x & 63;
    int wv = threadIdx.x >> 6;
    int t = blockIdx.x * 4 + wv;
    const float* xr = x + (size_t)t * HID;
    float acc[NE];
    #pragma unroll
    for (int e = 0; e < NE; ++e) acc[e] = 0.f;
    #pragma unroll
    for (int i = 0; i < 8; ++i) {
        f4 xv = *(const f4*)(xr + i * 256 + lane * 4);
        #pragma unroll
        for (int e = 0; e < NE; ++e) {
            f4 wv4 = *(const f4*)(rw + e * HID + i * 256 + lane * 4);
            acc[e] += xv.x * wv4.x + xv.y * wv4.y + xv.z * wv4.z + xv.w * wv4.w;
        }
    }
    #pragma unroll
    for (int off = 32; off; off >>= 1)
        #pragma unroll
        for (int e = 0; e < NE; ++e) acc[e] += __shfl_xor(acc[e], off, 64);
    if (lane == 0) {
        float lg[NE];
        #pragma unroll
        for (int e = 0; e < NE; ++e) lg[e] = acc[e] + rb[e];
        int i1 = 0;
        #pragma unroll
        for (int e = 1; e < NE; ++e) if (lg[e] > lg[i1]) i1 = e;
        int i2 = -1;
        #pragma unroll
        for (int e = 0; e < NE; ++e) {
            if (e == i1) continue;
            if (i2 < 0 || lg[e] > lg[i2]) i2 = e;
        }
        float ex = __expf(lg[i2] - lg[i1]);
        float w1 = 1.f / (1.f + ex);
        float w2 = ex / (1.f + ex);
        int p = atomicAdd(&cnt[i1], 1);
        tokL[i1 * TT + p] = t; slotL[i1 * TT + p] = t * 2;     gateL[i1 * TT + p] = w1;
        p = atomicAdd(&cnt[i2], 1);
        tokL[i2 * TT + p] = t; slotL[i2 * TT + p] = t * 2 + 1; gateL[i2 * TT + p] = w2;
    }
}

// ============================================================================
// 8-phase grouped GEMMs (m201 template port).
// Tile 256m x 256n-class, BK=64 K-tiles, 2-K-tile LDS double-buffer (128 KB):
//   dbuf d: A halves @ d*64KB + {0,16KB}; B halves @ d*64KB + 32KB + {0,16KB}.
// Half-tile = 128 rows x 64 cols bf16 (16 KB), staged by 2 gload16/thread
// (linear dest; inverse-swizzled global source col). Read swizzle:
// slot' = slot ^ (row&7) on 128B rows -> all 8 16B-slots uniformly hit.
// 8 waves (wr=wv>>2 -> A-half, wc=wv&3 -> 32-col slice of each B-half).
// Per K-tile quadrants (4 phases): Q(mh0,bh0) Q(mh0,bh1) Q(mh1,bh1) Q(mh1,bh0),
// 16 MFMA each; B-half0 re-read at ph4 (saves 16 VGPR).
// Stage schedule per iteration (T0=2it[d0], T1=2it+1[d1] computed):
//   ph1: d1.B0<-T1 | ph3: d0.B1<-T2 | ph4: d0.A0<-T2, vmcnt(4)
//   ph5: d0.A1,d0.B0<-T2 | ph7: d1.B1<-T3 | ph8: d1.A0,d1.A1<-T3, vmcnt(6)
// Frees: A-halves last read ph3/ph7; B0 ph4/ph8; B1 ph2/ph6 -> all stages
// target freed halves. Certs: ph4's vmcnt(4) covers ph5-8 reads (leaves
// ph3+ph4 in flight); ph8's vmcnt(6) covers next ph1-4 (leaves ph7+ph8).
// Tail: stages clamp k-offset (redundant but target-safe). Never drain in-loop.
// ============================================================================

#define RD_A(D, MH) { _Pragma("unroll") for (int f2 = 0; f2 < 4; ++f2) { \
    const char* _b = ldsc + (D)*65536 + aRB + ((MH)*4+f2)*2048; \
    af[f2*2]   = *(const s8v*)(_b + sw0); \
    af[f2*2+1] = *(const s8v*)(_b + sw1); } }

#define RD_B(D, BH) { _Pragma("unroll") for (int b2 = 0; b2 < 2; ++b2) { \
    const char* _b = ldsc + (D)*65536 + bRB + (BH)*16384 + b2*2048; \
    bf[b2*2]   = *(const s8v*)(_b + sw0); \
    bf[b2*2+1] = *(const s8v*)(_b + sw1); } }

#define PH_MFMA(MH, BH) \
    __builtin_amdgcn_s_setprio(1); \
    { _Pragma("unroll") for (int f2 = 0; f2 < 4; ++f2) \
      _Pragma("unroll") for (int b2 = 0; b2 < 2; ++b2) { \
        acc[(MH)*4+f2][(BH)*2+b2] = MFMA16(af[f2*2],   bf[b2*2],   acc[(MH)*4+f2][(BH)*2+b2]); \
        acc[(MH)*4+f2][(BH)*2+b2] = MFMA16(af[f2*2+1], bf[b2*2+1], acc[(MH)*4+f2][(BH)*2+b2]); } } \
    __builtin_amdgcn_s_setprio(0);

#define STG_A(D, H, T) { int ko = ((T) < NTK ? (T) : (NTK-1)) * 64; \
    gload16(pA##H##0 + ko, lds + (D)*32768 + (H)*8192 + tid8); \
    gload16(pA##H##1 + ko, lds + (D)*32768 + (H)*8192 + 4096 + tid8); }

#define STG_B(D, H, T) { int ko = ((T) < NTK ? (T) : (NTK-1)) * 64; \
    gload16(pB##H##0 + ko, lds + (D)*32768 + 16384 + (H)*8192 + tid8); \
    gload16(pB##H##1 + ko, lds + (D)*32768 + 16384 + (H)*8192 + 4096 + tid8); }

#define BAR_LGKM \
    __builtin_amdgcn_s_barrier(); \
    asm volatile("s_waitcnt lgkmcnt(0)" ::: "memory");

#define ENDP \
    __builtin_amdgcn_s_barrier(); \
    __builtin_amdgcn_sched_barrier(0);

// ---------- GEMM1: Hb[slot] = silu(X Wg^T) * (X Wu^T) ----------
// B-half0 = Wg[n0..n0+127], B-half1 = Wu[n0..n0+127]; wave wc owns logical
// cols wc*32..+32 of both -> acc[f][0..1]=g, acc[f][2..3]=u, silu in-lane.
__global__ __launch_bounds__(512, 2) void k_g1r(const unsigned short* __restrict__ xb,
                                                const unsigned short* __restrict__ WgB,
                                                const unsigned short* __restrict__ WuB,
                                                const int* __restrict__ cnt,
                                                const int* __restrict__ tokL,
                                                const int* __restrict__ slotL,
                                                unsigned short* __restrict__ Hb) {
    constexpr int NTK = 32;   // K-tiles (2048/64)
    constexpr int NI  = 16;   // iterations (2 K-tiles each)
    int bx = blockIdx.x;
    int e = bx / (32 * 44);
    int r = bx % (32 * 44);
    int mt = r / 44, nt = r % 44;
    int M = cnt[e];
    int m0 = mt * 256;
    if (m0 >= M) return;
    int n0 = nt * 128;

    __shared__ __align__(16) unsigned short lds[65536];   // 128 KB
    __shared__ int sTok[256];
    __shared__ int sSlot[256];

    int tid = threadIdx.x;
    if (tid < 256) {
        int m = m0 + tid;
        int mc = m < M ? m : M - 1;
        sTok[tid]  = tokL[e * TT + mc];
        sSlot[tid] = slotL[e * TT + mc];
    }
    __syncthreads();

    int wv = tid >> 6, lane = tid & 63;
    int tid8 = tid * 8;
    int srow = wv * 8 + (lane >> 3);
    int swc = ((lane & 7) ^ ((lane >> 3) & 7)) * 8;   // inverse-swizzled src col

    const unsigned short* pA00 = xb + (size_t)sTok[      srow] * HID + swc;
    const unsigned short* pA01 = xb + (size_t)sTok[ 64 + srow] * HID + swc;
    const unsigned short* pA10 = xb + (size_t)sTok[128 + srow] * HID + swc;
    const unsigned short* pA11 = xb + (size_t)sTok[192 + srow] * HID + swc;
    const unsigned short* pB00 = WgB + ((size_t)e * ITR + n0 +      srow) * HID + swc;
    const unsigned short* pB01 = WgB + ((size_t)e * ITR + n0 + 64 + srow) * HID + swc;
    const unsigned short* pB10 = WuB + ((size_t)e * ITR + n0 +      srow) * HID + swc;
    const unsigned short* pB11 = WuB + ((size_t)e * ITR + n0 + 64 + srow) * HID + swc;

    int wr = wv >> 2, wc = wv & 3;
    int lr = lane & 15, ls = lane >> 4;
    int sw0 = (ls ^ (lr & 7)) * 16;
    int sw1 = sw0 ^ 64;
    const char* ldsc = (const char*)lds;
    int aRB = wr * 16384 + lr * 128;
    int bRB = 32768 + wc * 4096 + lr * 128;

    s8v af[8], bf[4];
    acc4 acc[8][4];
    acc4 zero4 = {0.f, 0.f, 0.f, 0.f};
    #pragma unroll
    for (int f = 0; f < 8; ++f)
        #pragma unroll
        for (int b = 0; b < 4; ++b) acc[f][b] = zero4;

    // prologue: T0 all 4 halves, T1 {B1, A0, A1}
    STG_B(0, 0, 0); STG_B(0, 1, 0); STG_A(0, 0, 0); STG_A(0, 1, 0);
    STG_B(1, 1, 1); STG_A(1, 0, 1); STG_A(1, 1, 1);
    asm volatile("s_waitcnt vmcnt(6)" ::: "memory");   // T0 landed
    __builtin_amdgcn_s_barrier();
    __builtin_amdgcn_sched_barrier(0);

    #pragma unroll 1
    for (int it = 0; it < NI; ++it) {
        int t1 = 2 * it + 1, t2 = 2 * it + 2, t3 = 2 * it + 3;
        // ph1
        RD_A(0, 0); RD_B(0, 0);
        STG_B(1, 0, t1);
        BAR_LGKM; PH_MFMA(0, 0); ENDP;
        // ph2
        RD_B(0, 1);
        BAR_LGKM; PH_MFMA(0, 1); ENDP;
        // ph3
        RD_A(0, 1);
        STG_B(0, 1, t2);
        BAR_LGKM; PH_MFMA(1, 1); ENDP;
        // ph4
        RD_B(0, 0);
        STG_A(0, 0, t2);
        BAR_LGKM; PH_MFMA(1, 0);
        asm volatile("s_waitcnt vmcnt(4)" ::: "memory");
        ENDP;
        // ph5
        RD_A(1, 0); RD_B(1, 0);
        STG_A(0, 1, t2); STG_B(0, 0, t2);
        BAR_LGKM; PH_MFMA(0, 0); ENDP;
        // ph6
        RD_B(1, 1);
        BAR_LGKM; PH_MFMA(0, 1); ENDP;
        // ph7
        RD_A(1, 1);
        STG_B(1, 1, t3);
        BAR_LGKM; PH_MFMA(1, 1); ENDP;
        // ph8
        RD_B(1, 0);
        STG_A(1, 0, t3); STG_A(1, 1, t3);
        BAR_LGKM; PH_MFMA(1, 0);
        asm volatile("s_waitcnt vmcnt(6)" ::: "memory");
        ENDP;
    }
    asm volatile("s_waitcnt vmcnt(0)" ::: "memory");

    // epilogue: h = silu(g)*u in-lane
    #pragma unroll
    for (int f = 0; f < 8; ++f) {
        #pragma unroll
        for (int j = 0; j < 4; ++j) {
            int m = wr * 128 + f * 16 + ls * 4 + j;
            if (m0 + m < M) {
                size_t rowOff = (size_t)sSlot[m] * ITR + n0 + wc * 32 + lr;
                #pragma unroll
                for (int b = 0; b < 2; ++b) {
                    float g = acc[f][b][j], u = acc[f][b + 2][j];
                    float h = g * (1.f / (1.f + __expf(-g))) * u;
                    Hb[rowOff + b * 16] = f2bf(h);
                }
            }
        }
    }
}

// ---------- GEMM2: out[t] += gate * (Hb[slot] Wd^T) ----------
// Pure 256x256 tile; wave wc owns cols {n0+wc*32..+32} U {n0+128+wc*32..+32}.
__global__ __launch_bounds__(512, 2) void k_g2r(const unsigned short* __restrict__ Hb,
                                                const unsigned short* __restrict__ WdB,
                                                const int* __restrict__ cnt,
                                                const int* __restrict__ tokL,
                                                const int* __restrict__ slotL,
                                                const float* __restrict__ gateL,
                                                float* __restrict__ out) {
    constexpr int NTK = 88;   // 5632/64
    constexpr int NI  = 44;
    int bx = blockIdx.x;
    int e = bx / (32 * 8);
    int r = bx % (32 * 8);
    int mt = r / 8, nt = r % 8;
    int M = cnt[e];
    int m0 = mt * 256;
    if (m0 >= M) return;
    int n0 = nt * 256;

    __shared__ __align__(16) unsigned short lds[65536];
    __shared__ int sTok[256];
    __shared__ int sSlot[256];
    __shared__ float sGate[256];

    int tid = threadIdx.x;
    if (tid < 256) {
        int m = m0 + tid;
        int mc = m < M ? m : M - 1;
        sTok[tid]  = tokL[e * TT + mc];
        sSlot[tid] = slotL[e * TT + mc];
        sGate[tid] = gateL[e * TT + mc];
    }
    __syncthreads();

    int wv = tid >> 6, lane = tid & 63;
    int tid8 = tid * 8;
    int srow = wv * 8 + (lane >> 3);
    int swc = ((lane & 7) ^ ((lane >> 3) & 7)) * 8;

    const unsigned short* pA00 = Hb + (size_t)sSlot[      srow] * ITR + swc;
    const unsigned short* pA01 = Hb + (size_t)sSlot[ 64 + srow] * ITR + swc;
    const unsigned short* pA10 = Hb + (size_t)sSlot[128 + srow] * ITR + swc;
    const unsigned short* pA11 = Hb + (size_t)sSlot[192 + srow] * ITR + swc;
    const unsigned short* pB00 = WdB + ((size_t)e * HID + n0 +       srow) * ITR + swc;
    const unsigned short* pB01 = WdB + ((size_t)e * HID + n0 +  64 + srow) * ITR + swc;
    const unsigned short* pB10 = WdB + ((size_t)e * HID + n0 + 128 + srow) * ITR + swc;
    const unsigned short* pB11 = WdB + ((size_t)e * HID + n0 + 192 + srow) * ITR + swc;

    int wr = wv >> 2, wc = wv & 3;
    int lr = lane & 15, ls = lane >> 4;
    int sw0 = (ls ^ (lr & 7)) * 16;
    int sw1 = sw0 ^ 64;
    const char* ldsc = (const char*)lds;
    int aRB = wr * 16384 + lr * 128;
    int bRB = 32768 + wc * 4096 + lr * 128;

    s8v af[8], bf[4];
    acc4 acc[8][4];
    acc4 zero4 = {0.f, 0.f, 0.f, 0.f};
    #pragma unroll
    for (int f = 0; f < 8; ++f)
        #pragma unroll
        for (int b = 0; b < 4; ++b) acc[f][b] = zero4;

    STG_B(0, 0, 0); STG_B(0, 1, 0); STG_A(0, 0, 0); STG_A(0, 1, 0);
    STG_B(1, 1, 1); STG_A(1, 0, 1); STG_A(1, 1, 1);
    asm volatile("s_waitcnt vmcnt(6)" ::: "memory");
    __builtin_amdgcn_s_barrier();
    __builtin_amdgcn_sched_barrier(0);

    #pragma unroll 1
    for (int it = 0; it < NI; ++it) {
        int t1 = 2 * it + 1, t2 = 2 * it + 2, t3 = 2 * it + 3;
        RD_A(0, 0); RD_B(0, 0);
        STG_B(1, 0, t1);
        BAR_LGKM; PH_MFMA(0, 0); ENDP;
        RD_B(0, 1);
        BAR_LGKM; PH_MFMA(0, 1); ENDP;
        RD_A(0, 1);
        STG_B(0, 1, t2);
        BAR_LGKM; PH_MFMA(1, 1); ENDP;
        RD_B(0, 0);
        STG_A(0, 0, t2);
        BAR_LGKM; PH_MFMA(1, 0);
        asm volatile("s_waitcnt vmcnt(4)" ::: "memory");
        ENDP;
        RD_A(1, 0); RD_B(1, 0);
        STG_A(0, 1, t2); STG_B(0, 0, t2);
        BAR_LGKM; PH_MFMA(0, 0); ENDP;
        RD_B(1, 1);
        BAR_LGKM; PH_MFMA(0, 1); ENDP;
        RD_A(1, 1);
        STG_B(1, 1, t3);
        BAR_LGKM; PH_MFMA(1, 1); ENDP;
        RD_B(1, 0);
        STG_A(1, 0, t3); STG_A(1, 1, t3);
        BAR_LGKM; PH_MFMA(1, 0);
        asm volatile("s_waitcnt vmcnt(6)" ::: "memory");
        ENDP;
    }
    asm volatile("s_waitcnt vmcnt(0)" ::: "memory");

    #pragma unroll
    for (int f = 0; f < 8; ++f) {
        #pragma unroll
        for (int j = 0; j < 4; ++j) {
            int m = wr * 128 + f * 16 + ls * 4 + j;
            if (m0 + m < M) {
                int t = sTok[m];
                float w = sGate[m];
                float* o0 = out + (size_t)t * HID + n0 + wc * 32 + lr;
                atomicAdd(o0,      w * acc[f][0][j]);
                atomicAdd(o0 + 16, w * acc[f][1][j]);
                float* o1 = out + (size_t)t * HID + n0 + 128 + wc * 32 + lr;
                atomicAdd(o1,      w * acc[f][2][j]);
                atomicAdd(o1 + 16, w * acc[f][3][j]);
            }
        }
    }
}

// ============================================================================
// FALLBACK PATH (fp32 weights staged in-kernel) — only if ws too small.
// ============================================================================
#define BM 128
#define BN 128
#define BK 64
#define MT1 64
#define NT1 44
#define NT2 16

__global__ __launch_bounds__(256) void k_gemm1(const unsigned short* __restrict__ xb,
                                               const float* __restrict__ Wg,
                                               const float* __restrict__ Wu,
                                               const int* __restrict__ cnt,
                                               const int* __restrict__ tokL,
                                               const int* __restrict__ slotL,
                                               unsigned short* __restrict__ Hb) {
    int bx = blockIdx.x;
    int e = bx / (MT1 * NT1);
    int r = bx % (MT1 * NT1);
    int mt = r / NT1, nt = r % NT1;
    int M = cnt[e];
    int m0 = mt * BM;
    if (m0 >= M) return;
    int n0 = nt * BN;

    __shared__ __align__(16) unsigned short lA[BM * BK];
    __shared__ __align__(16) unsigned short lBg[BN * BK];
    __shared__ __align__(16) unsigned short lBu[BN * BK];
    __shared__ int sTok[BM];
    __shared__ int sSlot[BM];

    int tid = threadIdx.x;
    if (tid < BM) {
        int m = m0 + tid;
        int mc = m < M ? m : M - 1;
        sTok[tid] = tokL[e * TT + mc];
        sSlot[tid] = slotL[e * TT + mc];
    }
    __syncthreads();

    int ar = tid >> 3, ac = tid & 7;
    const unsigned short* aP[4];
    #pragma unroll
    for (int i = 0; i < 4; ++i)
        aP[i] = xb + (size_t)sTok[ar + 32 * i] * HID + ac * 8;

    int br = tid >> 4, bc = tid & 15;
    const float* gB = Wg + ((size_t)e * ITR + n0) * HID + bc * 4;
    const float* uB = Wu + ((size_t)e * ITR + n0) * HID + bc * 4;

    int wv = tid >> 6, lane = tid & 63;
    int wm = (wv >> 1) * 64, wn = (wv & 1) * 64;
    int lr = lane & 15, lk = (lane >> 4) * 8;

    acc4 zero4 = {0.f, 0.f, 0.f, 0.f};
    acc4 ag[4][4], au[4][4];
    #pragma unroll
    for (int mi = 0; mi < 4; ++mi)
        #pragma unroll
        for (int ni = 0; ni < 4; ++ni) { ag[mi][ni] = zero4; au[mi][ni] = zero4; }

    for (int k0 = 0; k0 < HID; k0 += BK) {
        if (k0) __syncthreads();
        #pragma unroll
        for (int i = 0; i < 4; ++i) {
            int row = ar + 32 * i;
            s8v v = *(const s8v*)(aP[i] + k0);
            int byt = (row * 128 + ac * 16) ^ ((row & 7) << 4);
            *(s8v*)((char*)lA + byt) = v;
        }
        #pragma unroll
        for (int i = 0; i < 8; ++i) {
            int row = br + 16 * i;
            f4 vg = *(const f4*)(gB + (size_t)row * HID + k0);
            f4 vu = *(const f4*)(uB + (size_t)row * HID + k0);
            u4v og = { f2bf(vg.x), f2bf(vg.y), f2bf(vg.z), f2bf(vg.w) };
            u4v ou = { f2bf(vu.x), f2bf(vu.y), f2bf(vu.z), f2bf(vu.w) };
            int byt = (row * 128 + bc * 8) ^ ((row & 7) << 4);
            *(u4v*)((char*)lBg + byt) = og;
            *(u4v*)((char*)lBu + byt) = ou;
        }
        __syncthreads();
        #pragma unroll
        for (int kk = 0; kk < BK; kk += 32) {
            s8v af2[4], gf[4], uf[4];
            #pragma unroll
            for (int i = 0; i < 4; ++i) {
                int rowA = wm + i * 16 + lr;
                af2[i] = *(const s8v*)((char*)lA + ((rowA * 128 + (kk + lk) * 2) ^ ((rowA & 7) << 4)));
                int rowB = wn + i * 16 + lr;
                int bb = (rowB * 128 + (kk + lk) * 2) ^ ((rowB & 7) << 4);
                gf[i] = *(const s8v*)((char*)lBg + bb);
                uf[i] = *(const s8v*)((char*)lBu + bb);
            }
            #pragma unroll
            for (int mi = 0; mi < 4; ++mi)
                #pragma unroll
                for (int ni = 0; ni < 4; ++ni) {
                    ag[mi][ni] = MFMA16(af2[mi], gf[ni], ag[mi][ni]);
                    au[mi][ni] = MFMA16(af2[mi], uf[ni], au[mi][ni]);
                }
        }
    }
    #pragma unroll
    for (int mi = 0; mi < 4; ++mi) {
        #pragma unroll
        for (int j = 0; j < 4; ++j) {
            int m = wm + mi * 16 + (lane >> 4) * 4 + j;
            if (m0 + m < M) {
                size_t rowOff = (size_t)sSlot[m] * ITR + n0 + wn + lr;
                #pragma unroll
                for (int ni = 0; ni < 4; ++ni) {
                    float g = ag[mi][ni][j], u = au[mi][ni][j];
                    float h = g * (1.f / (1.f + __expf(-g))) * u;
                    Hb[rowOff + ni * 16] = f2bf(h);
                }
            }
        }
    }
}

__global__ __launch_bounds__(256) void k_gemm2(const unsigned short* __restrict__ Hb,
                                               const float* __restrict__ Wd,
                                               const int* __restrict__ cnt,
                                               const int* __restrict__ tokL,
                                               const int* __restrict__ slotL,
                                               const float* __restrict__ gateL,
                                               float* __restrict__ out) {
    int bx = blockIdx.x;
    int e = bx / (MT1 * NT2);
    int r = bx % (MT1 * NT2);
    int mt = r / NT2, nt = r % NT2;
    int M = cnt[e];
    int m0 = mt * BM;
    if (m0 >= M) return;
    int n0 = nt * BN;

    __shared__ __align__(16) unsigned short lA[BM * BK];
    __shared__ __align__(16) unsigned short lB[BN * BK];
    __shared__ int sTok[BM];
    __shared__ int sSlot[BM];
    __shared__ float sGate[BM];

    int tid = threadIdx.x;
    if (tid < BM) {
        int m = m0 + tid;
        int mc = m < M ? m : M - 1;
        sTok[tid] = tokL[e * TT + mc];
        sSlot[tid] = slotL[e * TT + mc];
        sGate[tid] = gateL[e * TT + mc];
    }
    __syncthreads();

    int ar = tid >> 3, ac = tid & 7;
    const unsigned short* aP[4];
    #pragma unroll
    for (int i = 0; i < 4; ++i)
        aP[i] = Hb + (size_t)sSlot[ar + 32 * i] * ITR + ac * 8;

    int br = tid >> 4, bc = tid & 15;
    const float* dB = Wd + ((size_t)e * HID + n0) * ITR + bc * 4;

    int wv = tid >> 6, lane = tid & 63;
    int wm = (wv >> 1) * 64, wn = (wv & 1) * 64;
    int lr = lane & 15, lk = (lane >> 4) * 8;

    acc4 zero4 = {0.f, 0.f, 0.f, 0.f};
    acc4 a4[4][4];
    #pragma unroll
    for (int mi = 0; mi < 4; ++mi)
        #pragma unroll
        for (int ni = 0; ni < 4; ++ni) a4[mi][ni] = zero4;

    for (int k0 = 0; k0 < ITR; k0 += BK) {
        if (k0) __syncthreads();
        #pragma unroll
        for (int i = 0; i < 4; ++i) {
            int row = ar + 32 * i;
            s8v v = *(const s8v*)(aP[i] + k0);
            int byt = (row * 128 + ac * 16) ^ ((row & 7) << 4);
            *(s8v*)((char*)lA + byt) = v;
        }
        #pragma unroll
        for (int i = 0; i < 8; ++i) {
            int row = br + 16 * i;
            f4 vd = *(const f4*)(dB + (size_t)row * ITR + k0);
            u4v od = { f2bf(vd.x), f2bf(vd.y), f2bf(vd.z), f2bf(vd.w) };
            int byt = (row * 128 + bc * 8) ^ ((row & 7) << 4);
            *(u4v*)((char*)lB + byt) = od;
        }
        __syncthreads();
        #pragma unroll
        for (int kk = 0; kk < BK; kk += 32) {
            s8v af2[4], bf2[4];
            #pragma unroll
            for (int i = 0; i < 4; ++i) {
                int rowA = wm + i * 16 + lr;
                af2[i] = *(const s8v*)((char*)lA + ((rowA * 128 + (kk + lk) * 2) ^ ((rowA & 7) << 4)));
                int rowB = wn + i * 16 + lr;
                bf2[i] = *(const s8v*)((char*)lB + ((rowB * 128 + (kk + lk) * 2) ^ ((rowB & 7) << 4)));
            }
            #pragma unroll
            for (int mi = 0; mi < 4; ++mi)
                #pragma unroll
                for (int ni = 0; ni < 4; ++ni)
                    a4[mi][ni] = MFMA16(af2[mi], bf2[ni], a4[mi][ni]);
        }
    }
    #pragma unroll
    for (int mi = 0; mi < 4; ++mi) {
        #pragma unroll
        for (int j = 0; j < 4; ++j) {
            int m = wm + mi * 16 + (lane >> 4) * 4 + j;
            if (m0 + m < M) {
                int t = sTok[m];
                float w = sGate[m];
                float* orow = out + (size_t)t * HID + n0 + wn + lr;
                #pragma unroll
                for (int ni = 0; ni < 4; ++ni)
                    atomicAdd(orow + ni * 16, w * a4[mi][ni][j]);
            }
        }
    }
}

extern "C" void kernel_launch(void* const* d_in, const int* in_sizes, int n_in,
                              void* d_out, int out_size, void* d_ws, size_t ws_size,
                              hipStream_t stream) {
    const float* x  = (const float*)d_in[0];
    const float* rw = (const float*)d_in[1];
    const float* rb = (const float*)d_in[2];
    const float* Wg = (const float*)d_in[3];
    const float* Wu = (const float*)d_in[4];
    const float* Wd = (const float*)d_in[5];
    float* out = (float*)d_out;
    char* ws = (char*)d_ws;

    const size_t OFF_XB   = 0;                      // 32 MB
    const size_t OFF_HB   = 33554432ull;            // 176 MB
    const size_t OFF_TOK  = 218103808ull;
    const size_t OFF_SLOT = 218365952ull;
    const size_t OFF_GATE = 218628096ull;
    const size_t OFF_CNT  = 218890240ull;
    const size_t OFF_WG   = 218891264ull;           // 176 MB
    const size_t OFF_WU   = 403440640ull;           // 176 MB
    const size_t OFF_WD   = 587990016ull;           // 176 MB
    const size_t NEED     = 772539392ull;

    unsigned short* xb   = (unsigned short*)(ws + OFF_XB);
    unsigned short* Hb   = (unsigned short*)(ws + OFF_HB);
    int*   tokL  = (int*)(ws + OFF_TOK);
    int*   slotL = (int*)(ws + OFF_SLOT);
    float* gateL = (float*)(ws + OFF_GATE);
    int*   cnt   = (int*)(ws + OFF_CNT);

    hipMemsetAsync(cnt, 0, NE * sizeof(int), stream);
    hipMemsetAsync(out, 0, (size_t)out_size * sizeof(float), stream);
    k_cvt<<<8192, 256, 0, stream>>>(x, xb);
    k_router<<<2048, 256, 0, stream>>>(x, rw, rb, cnt, tokL, slotL, gateL);

    if (ws_size >= NEED) {
        unsigned short* WgB = (unsigned short*)(ws + OFF_WG);
        unsigned short* WuB = (unsigned short*)(ws + OFF_WU);
        unsigned short* WdB = (unsigned short*)(ws + OFF_WD);
        k_cvtW<<<3 * WBLK, 256, 0, stream>>>(Wg, Wu, Wd, WgB, WuB, WdB);
        k_g1r<<<NE * 32 * 44, 512, 0, stream>>>(xb, WgB, WuB, cnt, tokL, slotL, Hb);
        k_g2r<<<NE * 32 * 8, 512, 0, stream>>>(Hb, WdB, cnt, tokL, slotL, gateL, out);
    } else {
        k_gemm1<<<NE * MT1 * NT1, 256, 0, stream>>>(xb, Wg, Wu, cnt, tokL, slotL, Hb);
        k_gemm2<<<NE * MT1 * NT2, 256, 0, stream>>>(Hb, Wd, cnt, tokL, slotL, gateL, out);
    }
}

// Round 8
// 1806.000 us; speedup vs baseline: 1.1241x; 1.1241x over previous
//
#include <hip/hip_runtime.h>
#include <stdint.h>

#define HID 2048
#define ITR 5632
#define NE 8
#define TT 8192
#define BM 128
#define BN 128
#define BK 64
#define MT1 64          // max m-tiles per expert (8192/128)
#define NT1 44          // ITR/BN
#define NT2 16          // HID/BN

typedef __attribute__((ext_vector_type(4))) float f4;
typedef __attribute__((ext_vector_type(8))) short s8v;      // 8 bf16 (MFMA frag)
typedef __attribute__((ext_vector_type(4))) float acc4;     // MFMA accum
typedef __attribute__((ext_vector_type(4))) unsigned short u4v;
typedef __attribute__((ext_vector_type(8))) unsigned short u8v;

__device__ __forceinline__ unsigned short f2bf(float f) {
    union { float f; uint32_t u; } v; v.f = f;
    uint32_t u = v.u;
    return (unsigned short)((u + 0x7FFFu + ((u >> 16) & 1u)) >> 16);
}

__device__ __forceinline__ void gload16(const unsigned short* g, unsigned short* l) {
    __builtin_amdgcn_global_load_lds(
        (const __attribute__((address_space(1))) unsigned int*)g,
        (__attribute__((address_space(3))) unsigned int*)l, 16, 0, 0);
}

#define MFMA16(a, b, c) __builtin_amdgcn_mfma_f32_16x16x32_bf16(a, b, c, 0, 0, 0)

// ---------- fused: x fp32 -> bf16 AND router top-2 ----------
// 4 waves/block, 1 token/wave. x is loaded ONCE (f4/lane), used for both the
// bf16 store and the 8 router dot-products.
__global__ __launch_bounds__(256) void k_xrt(const float* __restrict__ x,
                                             const float* __restrict__ rw,
                                             const float* __restrict__ rb,
                                             unsigned short* __restrict__ xb,
                                             int* __restrict__ cnt,
                                             int* __restrict__ tokL,
                                             int* __restrict__ slotL,
                                             float* __restrict__ gateL) {
    int lane = threadIdx.x & 63;
    int wv = threadIdx.x >> 6;
    int t = blockIdx.x * 4 + wv;
    const float* xr = x + (size_t)t * HID;
    unsigned short* xo = xb + (size_t)t * HID;
    float acc[NE];
    #pragma unroll
    for (int e = 0; e < NE; ++e) acc[e] = 0.f;
    #pragma unroll
    for (int i = 0; i < 8; ++i) {
        f4 xv = *(const f4*)(xr + i * 256 + lane * 4);
        u4v o = { f2bf(xv.x), f2bf(xv.y), f2bf(xv.z), f2bf(xv.w) };
        *(u4v*)(xo + i * 256 + lane * 4) = o;
        #pragma unroll
        for (int e = 0; e < NE; ++e) {
            f4 wv4 = *(const f4*)(rw + e * HID + i * 256 + lane * 4);
            acc[e] += xv.x * wv4.x + xv.y * wv4.y + xv.z * wv4.z + xv.w * wv4.w;
        }
    }
    #pragma unroll
    for (int off = 32; off; off >>= 1)
        #pragma unroll
        for (int e = 0; e < NE; ++e) acc[e] += __shfl_xor(acc[e], off, 64);
    if (lane == 0) {
        float lg[NE];
        #pragma unroll
        for (int e = 0; e < NE; ++e) lg[e] = acc[e] + rb[e];
        int i1 = 0;
        #pragma unroll
        for (int e = 1; e < NE; ++e) if (lg[e] > lg[i1]) i1 = e;   // earliest max (jax tie rule)
        int i2 = -1;
        #pragma unroll
        for (int e = 0; e < NE; ++e) {
            if (e == i1) continue;
            if (i2 < 0 || lg[e] > lg[i2]) i2 = e;
        }
        float ex = __expf(lg[i2] - lg[i1]);   // <= 1
        float w1 = 1.f / (1.f + ex);
        float w2 = ex / (1.f + ex);
        int p = atomicAdd(&cnt[i1], 1);
        tokL[i1 * TT + p] = t; slotL[i1 * TT + p] = t * 2;     gateL[i1 * TT + p] = w1;
        p = atomicAdd(&cnt[i2], 1);
        tokL[i2 * TT + p] = t; slotL[i2 * TT + p] = t * 2 + 1; gateL[i2 * TT + p] = w2;
    }
}

// ---------- all three weight tensors fp32 -> bf16, one launch ----------
#define WBLK 45056      // (NE*ITR*HID)/(8*256) blocks per tensor
__global__ __launch_bounds__(256) void k_cvtW(const float* __restrict__ a,
                                              const float* __restrict__ b,
                                              const float* __restrict__ c,
                                              unsigned short* __restrict__ oa,
                                              unsigned short* __restrict__ ob,
                                              unsigned short* __restrict__ oc) {
    int bb = blockIdx.x;
    const float* s; unsigned short* d;
    if (bb < WBLK)            { s = a; d = oa; }
    else if (bb < 2 * WBLK)   { s = b; d = ob; bb -= WBLK; }
    else                      { s = c; d = oc; bb -= 2 * WBLK; }
    size_t i = ((size_t)bb * 256 + threadIdx.x) * 8;
    f4 va = *(const f4*)(s + i);
    f4 vb = *(const f4*)(s + i + 4);
    u8v o;
    o[0]=f2bf(va.x); o[1]=f2bf(va.y); o[2]=f2bf(va.z); o[3]=f2bf(va.w);
    o[4]=f2bf(vb.x); o[5]=f2bf(vb.y); o[6]=f2bf(vb.z); o[7]=f2bf(vb.w);
    *(u8v*)(d + i) = o;
}

// ---------- plain x fp32 -> bf16 (fallback path only) ----------
__global__ __launch_bounds__(256) void k_cvt(const float* __restrict__ src,
                                             unsigned short* __restrict__ dst) {
    size_t i = ((size_t)blockIdx.x * 256 + threadIdx.x) * 8;
    f4 a = *(const f4*)(src + i);
    f4 b = *(const f4*)(src + i + 4);
    u8v o;
    o[0]=f2bf(a.x); o[1]=f2bf(a.y); o[2]=f2bf(a.z); o[3]=f2bf(a.w);
    o[4]=f2bf(b.x); o[5]=f2bf(b.y); o[6]=f2bf(b.z); o[7]=f2bf(b.w);
    *(u8v*)(dst + i) = o;
}

// ============================================================================
// FAST PATH (round-2 measured best): bf16 weights, global_load_lds staging,
// 128x128 tile, BK=64, XOR swizzle ^((row&7)<<4), linear grid (nt fastest).
// ============================================================================

// ---------- GEMM1: Hb[slot] = silu(X Wg^T) * (X Wu^T), bf16 ----------
__global__ __launch_bounds__(256, 2) void k_gemm1b(const unsigned short* __restrict__ xb,
                                                   const unsigned short* __restrict__ WgB,
                                                   const unsigned short* __restrict__ WuB,
                                                   const int* __restrict__ cnt,
                                                   const int* __restrict__ tokL,
                                                   const int* __restrict__ slotL,
                                                   unsigned short* __restrict__ Hb) {
    int bx = blockIdx.x;
    int e = bx / (MT1 * NT1);
    int r = bx % (MT1 * NT1);
    int mt = r / NT1, nt = r % NT1;
    int M = cnt[e];
    int m0 = mt * BM;
    if (m0 >= M) return;
    int n0 = nt * BN;

    __shared__ __align__(16) unsigned short lA[BM * BK];
    __shared__ __align__(16) unsigned short lBg[BN * BK];
    __shared__ __align__(16) unsigned short lBu[BN * BK];
    __shared__ int sTok[BM];
    __shared__ int sSlot[BM];

    int tid = threadIdx.x;
    if (tid < BM) {
        int m = m0 + tid;
        int mc = m < M ? m : M - 1;
        sTok[tid] = tokL[e * TT + mc];
        sSlot[tid] = slotL[e * TT + mc];
    }
    __syncthreads();

    int wv = tid >> 6, lane = tid & 63;
    int subrow = lane >> 3;                      // 0..7 = row within 8-row chunk
    int colE = ((lane & 7) ^ subrow) * 8;        // inverse-swizzled source col (elems)

    const unsigned short* aSrc[4];
    const unsigned short* gSrc[4];
    const unsigned short* uSrc[4];
    #pragma unroll
    for (int i = 0; i < 4; ++i) {
        int row = (i * 4 + wv) * 8 + subrow;
        aSrc[i] = xb + (size_t)sTok[row] * HID + colE;
        gSrc[i] = WgB + ((size_t)e * ITR + n0 + row) * HID + colE;
        uSrc[i] = WuB + ((size_t)e * ITR + n0 + row) * HID + colE;
    }

    int wm = (wv >> 1) * 64, wn = (wv & 1) * 64;
    int lr = lane & 15, lk = (lane >> 4) * 8;

    acc4 zero4 = {0.f, 0.f, 0.f, 0.f};
    acc4 ag[4][4], au[4][4];
    #pragma unroll
    for (int mi = 0; mi < 4; ++mi)
        #pragma unroll
        for (int ni = 0; ni < 4; ++ni) { ag[mi][ni] = zero4; au[mi][ni] = zero4; }

    for (int k0 = 0; k0 < HID; k0 += BK) {
        if (k0) __syncthreads();
        #pragma unroll
        for (int i = 0; i < 4; ++i) {
            gload16(aSrc[i] + k0, lA  + (i * 4 + wv) * 512);
            gload16(gSrc[i] + k0, lBg + (i * 4 + wv) * 512);
            gload16(uSrc[i] + k0, lBu + (i * 4 + wv) * 512);
        }
        __syncthreads();
        #pragma unroll
        for (int kk = 0; kk < BK; kk += 32) {
            s8v af[4], gf[4], uf[4];
            #pragma unroll
            for (int i = 0; i < 4; ++i) {
                int rowA = wm + i * 16 + lr;
                af[i] = *(const s8v*)((char*)lA + ((rowA * 128 + (kk + lk) * 2) ^ ((rowA & 7) << 4)));
                int rowB = wn + i * 16 + lr;
                int bb = (rowB * 128 + (kk + lk) * 2) ^ ((rowB & 7) << 4);
                gf[i] = *(const s8v*)((char*)lBg + bb);
                uf[i] = *(const s8v*)((char*)lBu + bb);
            }
            #pragma unroll
            for (int mi = 0; mi < 4; ++mi)
                #pragma unroll
                for (int ni = 0; ni < 4; ++ni) {
                    ag[mi][ni] = MFMA16(af[mi], gf[ni], ag[mi][ni]);
                    au[mi][ni] = MFMA16(af[mi], uf[ni], au[mi][ni]);
                }
        }
    }
    #pragma unroll
    for (int mi = 0; mi < 4; ++mi) {
        #pragma unroll
        for (int j2 = 0; j2 < 4; ++j2) {
            int m = wm + mi * 16 + (lane >> 4) * 4 + j2;
            if (m0 + m < M) {
                size_t rowOff = (size_t)sSlot[m] * ITR + n0 + wn + lr;
                #pragma unroll
                for (int ni = 0; ni < 4; ++ni) {
                    float g = ag[mi][ni][j2], u = au[mi][ni][j2];
                    float h = g * (1.f / (1.f + __expf(-g))) * u;
                    Hb[rowOff + ni * 16] = f2bf(h);
                }
            }
        }
    }
}

// ---------- GEMM2: out[t] += gate * (Hb[slot] Wd^T) ----------
__global__ __launch_bounds__(256, 3) void k_gemm2b(const unsigned short* __restrict__ Hb,
                                                   const unsigned short* __restrict__ WdB,
                                                   const int* __restrict__ cnt,
                                                   const int* __restrict__ tokL,
                                                   const int* __restrict__ slotL,
                                                   const float* __restrict__ gateL,
                                                   float* __restrict__ out) {
    int bx = blockIdx.x;
    int e = bx / (MT1 * NT2);
    int r = bx % (MT1 * NT2);
    int mt = r / NT2, nt = r % NT2;
    int M = cnt[e];
    int m0 = mt * BM;
    if (m0 >= M) return;
    int n0 = nt * BN;

    __shared__ __align__(16) unsigned short lA[BM * BK];
    __shared__ __align__(16) unsigned short lB[BN * BK];
    __shared__ int sTok[BM];
    __shared__ int sSlot[BM];
    __shared__ float sGate[BM];

    int tid = threadIdx.x;
    if (tid < BM) {
        int m = m0 + tid;
        int mc = m < M ? m : M - 1;
        sTok[tid] = tokL[e * TT + mc];
        sSlot[tid] = slotL[e * TT + mc];
        sGate[tid] = gateL[e * TT + mc];
    }
    __syncthreads();

    int wv = tid >> 6, lane = tid & 63;
    int subrow = lane >> 3;
    int colE = ((lane & 7) ^ subrow) * 8;

    const unsigned short* aSrc[4];
    const unsigned short* bSrc[4];
    #pragma unroll
    for (int i = 0; i < 4; ++i) {
        int row = (i * 4 + wv) * 8 + subrow;
        aSrc[i] = Hb + (size_t)sSlot[row] * ITR + colE;
        bSrc[i] = WdB + ((size_t)e * HID + n0 + row) * ITR + colE;
    }

    int wm = (wv >> 1) * 64, wn = (wv & 1) * 64;
    int lr = lane & 15, lk = (lane >> 4) * 8;

    acc4 zero4 = {0.f, 0.f, 0.f, 0.f};
    acc4 a4[4][4];
    #pragma unroll
    for (int mi = 0; mi < 4; ++mi)
        #pragma unroll
        for (int ni = 0; ni < 4; ++ni) a4[mi][ni] = zero4;

    for (int k0 = 0; k0 < ITR; k0 += BK) {
        if (k0) __syncthreads();
        #pragma unroll
        for (int i = 0; i < 4; ++i) {
            gload16(aSrc[i] + k0, lA + (i * 4 + wv) * 512);
            gload16(bSrc[i] + k0, lB + (i * 4 + wv) * 512);
        }
        __syncthreads();
        #pragma unroll
        for (int kk = 0; kk < BK; kk += 32) {
            s8v af[4], bf[4];
            #pragma unroll
            for (int i = 0; i < 4; ++i) {
                int rowA = wm + i * 16 + lr;
                af[i] = *(const s8v*)((char*)lA + ((rowA * 128 + (kk + lk) * 2) ^ ((rowA & 7) << 4)));
                int rowB = wn + i * 16 + lr;
                bf[i] = *(const s8v*)((char*)lB + ((rowB * 128 + (kk + lk) * 2) ^ ((rowB & 7) << 4)));
            }
            #pragma unroll
            for (int mi = 0; mi < 4; ++mi)
                #pragma unroll
                for (int ni = 0; ni < 4; ++ni)
                    a4[mi][ni] = MFMA16(af[mi], bf[ni], a4[mi][ni]);
        }
    }
    #pragma unroll
    for (int mi = 0; mi < 4; ++mi) {
        #pragma unroll
        for (int j2 = 0; j2 < 4; ++j2) {
            int m = wm + mi * 16 + (lane >> 4) * 4 + j2;
            if (m0 + m < M) {
                int t = sTok[m];
                float w = sGate[m];
                float* orow = out + (size_t)t * HID + n0 + wn + lr;
                #pragma unroll
                for (int ni = 0; ni < 4; ++ni)
                    atomicAdd(orow + ni * 16, w * a4[mi][ni][j2]);
            }
        }
    }
}

// ============================================================================
// FALLBACK PATH (fp32 weights staged in-kernel) — only if ws too small.
// ============================================================================

__global__ __launch_bounds__(256) void k_gemm1(const unsigned short* __restrict__ xb,
                                               const float* __restrict__ Wg,
                                               const float* __restrict__ Wu,
                                               const int* __restrict__ cnt,
                                               const int* __restrict__ tokL,
                                               const int* __restrict__ slotL,
                                               unsigned short* __restrict__ Hb) {
    int bx = blockIdx.x;
    int e = bx / (MT1 * NT1);
    int r = bx % (MT1 * NT1);
    int mt = r / NT1, nt = r % NT1;
    int M = cnt[e];
    int m0 = mt * BM;
    if (m0 >= M) return;
    int n0 = nt * BN;

    __shared__ __align__(16) unsigned short lA[BM * BK];
    __shared__ __align__(16) unsigned short lBg[BN * BK];
    __shared__ __align__(16) unsigned short lBu[BN * BK];
    __shared__ int sTok[BM];
    __shared__ int sSlot[BM];

    int tid = threadIdx.x;
    if (tid < BM) {
        int m = m0 + tid;
        int mc = m < M ? m : M - 1;
        sTok[tid] = tokL[e * TT + mc];
        sSlot[tid] = slotL[e * TT + mc];
    }
    __syncthreads();

    int ar = tid >> 3, ac = tid & 7;
    const unsigned short* aP[4];
    #pragma unroll
    for (int i = 0; i < 4; ++i)
        aP[i] = xb + (size_t)sTok[ar + 32 * i] * HID + ac * 8;

    int br = tid >> 4, bc = tid & 15;
    const float* gB = Wg + ((size_t)e * ITR + n0) * HID + bc * 4;
    const float* uB = Wu + ((size_t)e * ITR + n0) * HID + bc * 4;

    int wv = tid >> 6, lane = tid & 63;
    int wm = (wv >> 1) * 64, wn = (wv & 1) * 64;
    int lr = lane & 15, lk = (lane >> 4) * 8;

    acc4 zero4 = {0.f, 0.f, 0.f, 0.f};
    acc4 ag[4][4], au[4][4];
    #pragma unroll
    for (int mi = 0; mi < 4; ++mi)
        #pragma unroll
        for (int ni = 0; ni < 4; ++ni) { ag[mi][ni] = zero4; au[mi][ni] = zero4; }

    for (int k0 = 0; k0 < HID; k0 += BK) {
        if (k0) __syncthreads();
        #pragma unroll
        for (int i = 0; i < 4; ++i) {
            int row = ar + 32 * i;
            s8v v = *(const s8v*)(aP[i] + k0);
            int byt = (row * 128 + ac * 16) ^ ((row & 7) << 4);
            *(s8v*)((char*)lA + byt) = v;
        }
        #pragma unroll
        for (int i = 0; i < 8; ++i) {
            int row = br + 16 * i;
            f4 vg = *(const f4*)(gB + (size_t)row * HID + k0);
            f4 vu = *(const f4*)(uB + (size_t)row * HID + k0);
            u4v og = { f2bf(vg.x), f2bf(vg.y), f2bf(vg.z), f2bf(vg.w) };
            u4v ou = { f2bf(vu.x), f2bf(vu.y), f2bf(vu.z), f2bf(vu.w) };
            int byt = (row * 128 + bc * 8) ^ ((row & 7) << 4);
            *(u4v*)((char*)lBg + byt) = og;
            *(u4v*)((char*)lBu + byt) = ou;
        }
        __syncthreads();
        #pragma unroll
        for (int kk = 0; kk < BK; kk += 32) {
            s8v af[4], gf[4], uf[4];
            #pragma unroll
            for (int i = 0; i < 4; ++i) {
                int rowA = wm + i * 16 + lr;
                af[i] = *(const s8v*)((char*)lA + ((rowA * 128 + (kk + lk) * 2) ^ ((rowA & 7) << 4)));
                int rowB = wn + i * 16 + lr;
                int bb = (rowB * 128 + (kk + lk) * 2) ^ ((rowB & 7) << 4);
                gf[i] = *(const s8v*)((char*)lBg + bb);
                uf[i] = *(const s8v*)((char*)lBu + bb);
            }
            #pragma unroll
            for (int mi = 0; mi < 4; ++mi)
                #pragma unroll
                for (int ni = 0; ni < 4; ++ni) {
                    ag[mi][ni] = MFMA16(af[mi], gf[ni], ag[mi][ni]);
                    au[mi][ni] = MFMA16(af[mi], uf[ni], au[mi][ni]);
                }
        }
    }
    #pragma unroll
    for (int mi = 0; mi < 4; ++mi) {
        #pragma unroll
        for (int j = 0; j < 4; ++j) {
            int m = wm + mi * 16 + (lane >> 4) * 4 + j;
            if (m0 + m < M) {
                size_t rowOff = (size_t)sSlot[m] * ITR + n0 + wn + lr;
                #pragma unroll
                for (int ni = 0; ni < 4; ++ni) {
                    float g = ag[mi][ni][j], u = au[mi][ni][j];
                    float h = g * (1.f / (1.f + __expf(-g))) * u;
                    Hb[rowOff + ni * 16] = f2bf(h);
                }
            }
        }
    }
}

__global__ __launch_bounds__(256) void k_gemm2(const unsigned short* __restrict__ Hb,
                                               const float* __restrict__ Wd,
                                               const int* __restrict__ cnt,
                                               const int* __restrict__ tokL,
                                               const int* __restrict__ slotL,
                                               const float* __restrict__ gateL,
                                               float* __restrict__ out) {
    int bx = blockIdx.x;
    int e = bx / (MT1 * NT2);
    int r = bx % (MT1 * NT2);
    int mt = r / NT2, nt = r % NT2;
    int M = cnt[e];
    int m0 = mt * BM;
    if (m0 >= M) return;
    int n0 = nt * BN;

    __shared__ __align__(16) unsigned short lA[BM * BK];
    __shared__ __align__(16) unsigned short lB[BN * BK];
    __shared__ int sTok[BM];
    __shared__ int sSlot[BM];
    __shared__ float sGate[BM];

    int tid = threadIdx.x;
    if (tid < BM) {
        int m = m0 + tid;
        int mc = m < M ? m : M - 1;
        sTok[tid] = tokL[e * TT + mc];
        sSlot[tid] = slotL[e * TT + mc];
        sGate[tid] = gateL[e * TT + mc];
    }
    __syncthreads();

    int ar = tid >> 3, ac = tid & 7;
    const unsigned short* aP[4];
    #pragma unroll
    for (int i = 0; i < 4; ++i)
        aP[i] = Hb + (size_t)sSlot[ar + 32 * i] * ITR + ac * 8;

    int br = tid >> 4, bc = tid & 15;
    const float* dB = Wd + ((size_t)e * HID + n0) * ITR + bc * 4;

    int wv = tid >> 6, lane = tid & 63;
    int wm = (wv >> 1) * 64, wn = (wv & 1) * 64;
    int lr = lane & 15, lk = (lane >> 4) * 8;

    acc4 zero4 = {0.f, 0.f, 0.f, 0.f};
    acc4 a4[4][4];
    #pragma unroll
    for (int mi = 0; mi < 4; ++mi)
        #pragma unroll
        for (int ni = 0; ni < 4; ++ni) a4[mi][ni] = zero4;

    for (int k0 = 0; k0 < ITR; k0 += BK) {
        if (k0) __syncthreads();
        #pragma unroll
        for (int i = 0; i < 4; ++i) {
            int row = ar + 32 * i;
            s8v v = *(const s8v*)(aP[i] + k0);
            int byt = (row * 128 + ac * 16) ^ ((row & 7) << 4);
            *(s8v*)((char*)lA + byt) = v;
        }
        #pragma unroll
        for (int i = 0; i < 8; ++i) {
            int row = br + 16 * i;
            f4 vd = *(const f4*)(dB + (size_t)row * ITR + k0);
            u4v od = { f2bf(vd.x), f2bf(vd.y), f2bf(vd.z), f2bf(vd.w) };
            int byt = (row * 128 + bc * 8) ^ ((row & 7) << 4);
            *(u4v*)((char*)lB + byt) = od;
        }
        __syncthreads();
        #pragma unroll
        for (int kk = 0; kk < BK; kk += 32) {
            s8v af[4], bf[4];
            #pragma unroll
            for (int i = 0; i < 4; ++i) {
                int rowA = wm + i * 16 + lr;
                af[i] = *(const s8v*)((char*)lA + ((rowA * 128 + (kk + lk) * 2) ^ ((rowA & 7) << 4)));
                int rowB = wn + i * 16 + lr;
                bf[i] = *(const s8v*)((char*)lB + ((rowB * 128 + (kk + lk) * 2) ^ ((rowB & 7) << 4)));
            }
            #pragma unroll
            for (int mi = 0; mi < 4; ++mi)
                #pragma unroll
                for (int ni = 0; ni < 4; ++ni)
                    a4[mi][ni] = MFMA16(af[mi], bf[ni], a4[mi][ni]);
        }
    }
    #pragma unroll
    for (int mi = 0; mi < 4; ++mi) {
        #pragma unroll
        for (int j = 0; j < 4; ++j) {
            int m = wm + mi * 16 + (lane >> 4) * 4 + j;
            if (m0 + m < M) {
                int t = sTok[m];
                float w = sGate[m];
                float* orow = out + (size_t)t * HID + n0 + wn + lr;
                #pragma unroll
                for (int ni = 0; ni < 4; ++ni)
                    atomicAdd(orow + ni * 16, w * a4[mi][ni][j]);
            }
        }
    }
}

extern "C" void kernel_launch(void* const* d_in, const int* in_sizes, int n_in,
                              void* d_out, int out_size, void* d_ws, size_t ws_size,
                              hipStream_t stream) {
    const float* x  = (const float*)d_in[0];
    const float* rw = (const float*)d_in[1];
    const float* rb = (const float*)d_in[2];
    const float* Wg = (const float*)d_in[3];
    const float* Wu = (const float*)d_in[4];
    const float* Wd = (const float*)d_in[5];
    float* out = (float*)d_out;
    char* ws = (char*)d_ws;

    // ws layout (bytes):
    const size_t OFF_XB   = 0;                      // 32 MB
    const size_t OFF_HB   = 33554432ull;            // 176 MB
    const size_t OFF_TOK  = 218103808ull;
    const size_t OFF_SLOT = 218365952ull;
    const size_t OFF_GATE = 218628096ull;
    const size_t OFF_CNT  = 218890240ull;
    const size_t OFF_WG   = 218891264ull;           // 176 MB
    const size_t OFF_WU   = 403440640ull;           // 176 MB
    const size_t OFF_WD   = 587990016ull;           // 176 MB
    const size_t NEED     = 772539392ull;

    unsigned short* xb   = (unsigned short*)(ws + OFF_XB);
    unsigned short* Hb   = (unsigned short*)(ws + OFF_HB);
    int*   tokL  = (int*)(ws + OFF_TOK);
    int*   slotL = (int*)(ws + OFF_SLOT);
    float* gateL = (float*)(ws + OFF_GATE);
    int*   cnt   = (int*)(ws + OFF_CNT);

    hipMemsetAsync(cnt, 0, NE * sizeof(int), stream);
    hipMemsetAsync(out, 0, (size_t)out_size * sizeof(float), stream);
    k_xrt<<<2048, 256, 0, stream>>>(x, rw, rb, xb, cnt, tokL, slotL, gateL);

    if (ws_size >= NEED) {
        unsigned short* WgB = (unsigned short*)(ws + OFF_WG);
        unsigned short* WuB = (unsigned short*)(ws + OFF_WU);
        unsigned short* WdB = (unsigned short*)(ws + OFF_WD);
        k_cvtW<<<3 * WBLK, 256, 0, stream>>>(Wg, Wu, Wd, WgB, WuB, WdB);
        k_gemm1b<<<NE * MT1 * NT1, 256, 0, stream>>>(xb, WgB, WuB, cnt, tokL, slotL, Hb);
        k_gemm2b<<<NE * MT1 * NT2, 256, 0, stream>>>(Hb, WdB, cnt, tokL, slotL, gateL, out);
    } else {
        k_gemm1<<<NE * MT1 * NT1, 256, 0, stream>>>(xb, Wg, Wu, cnt, tokL, slotL, Hb);
        k_gemm2<<<NE * MT1 * NT2, 256, 0, stream>>>(Hb, Wd, cnt, tokL, slotL, gateL, out);
    }
}